// Round 4
// baseline (908.208 us; speedup 1.0000x reference)
//
#include <hip/hip_runtime.h>

typedef float fvec4 __attribute__((ext_vector_type(4)));

#define NBLK 256
#define TPB  512
#define CN   512            // nodes per chunk

// ---- LDS layout (float offsets), all table offsets multiple of 4 ----
#define O_E0_2 0            // 96*86  = 8256
#define O_E0_3 8256         // 8*85   = 680
#define O_E0_5 8936         // 2*85   = 170  (pad 2)
#define O_E1_2 9108         // 4*128  = 512
#define O_E1_3 9620         // 22*128 = 2816
#define O_E2_0 12436        // 6*256  = 1536
#define O_E3_0 13972        // 15*128 = 1920
#define O_E3_1 15892        // 96*128 = 12288
#define NTAB   28180
#define XSH    NTAB                 // CN*16 floats (rows padded 14->16)
#define TSH    (XSH + CN * 16)      // CN ints
#define SMEM_FLOATS (TSH + CN)      // 36884
#define SMEM_BYTES  (SMEM_FLOATS * 4)   // 147536 B < 160 KiB

extern __shared__ float smem[];

__global__ __launch_bounds__(TPB, 1)
void node_enc_kernel(const float* __restrict__ x,
                     const int* __restrict__ node_types,
                     const float* __restrict__ W0, const float* __restrict__ b0,
                     const float* __restrict__ E0_2, const float* __restrict__ E0_3,
                     const float* __restrict__ E0_5,
                     const float* __restrict__ W1, const float* __restrict__ b1,
                     const float* __restrict__ E1_2, const float* __restrict__ E1_3,
                     const float* __restrict__ W2, const float* __restrict__ b2,
                     const float* __restrict__ E2_0,
                     const float* __restrict__ W3, const float* __restrict__ b3,
                     const float* __restrict__ E3_0, const float* __restrict__ E3_1,
                     float* __restrict__ out, int n_nodes)
{
    const int tid = threadIdx.x;
    const int e   = tid & 255;   // output column owned by this thread
    const int h   = tid >> 8;    // which 256-node half of the chunk

    // ---------- copy all embedding tables into LDS (once per block) ----------
    auto copy_tab = [&](const float* __restrict__ src, int dst, int n) {
        if ((((uintptr_t)src) & 15) == 0) {
            const int nv = n >> 2;
            for (int i = tid; i < nv; i += TPB) {
                const fvec4 v = *(reinterpret_cast<const fvec4*>(src) + i);
                *reinterpret_cast<fvec4*>(&smem[dst + (i << 2)]) = v;
            }
            for (int i = (nv << 2) + tid; i < n; i += TPB) smem[dst + i] = src[i];
        } else {
            for (int i = tid; i < n; i += TPB) smem[dst + i] = src[i];
        }
    };
    copy_tab(E0_2, O_E0_2, 8256);
    copy_tab(E0_3, O_E0_3, 680);
    copy_tab(E0_5, O_E0_5, 170);
    copy_tab(E1_2, O_E1_2, 512);
    copy_tab(E1_3, O_E1_3, 2816);
    copy_tab(E2_0, O_E2_0, 1536);
    copy_tab(E3_0, O_E3_0, 1920);
    copy_tab(E3_1, O_E3_1, 12288);

    // ---------- per-column weights for all 4 types -> registers ----------
    float w0[11], w1[12], w2[12], w3[12];
    #pragma unroll
    for (int k = 0; k < 11; ++k) w0[k] = W0[e * 11 + k];
    #pragma unroll
    for (int k = 0; k < 12; ++k) w1[k] = W1[e * 12 + k];
    #pragma unroll
    for (int k = 0; k < 12; ++k) w2[k] = W2[e * 12 + k];
    #pragma unroll
    for (int k = 0; k < 12; ++k) w3[k] = W3[e * 12 + k];
    const float bias0 = b0[e], bias1 = b1[e], bias2 = b2[e], bias3 = b3[e];

    // ---------- per-thread embedding descriptors (LDS float offsets) ----------
    int sc0, st0, pb0;
    if (e < 86)       { sc0 = 2; st0 = 86; pb0 = O_E0_2 + e; }
    else if (e < 171) { sc0 = 3; st0 = 85; pb0 = O_E0_3 + (e - 86); }
    else              { sc0 = 5; st0 = 85; pb0 = O_E0_5 + (e - 171); }
    int sc1, st1, pb1;
    if (e < 128) { sc1 = 2; st1 = 128; pb1 = O_E1_2 + e; }
    else         { sc1 = 3; st1 = 128; pb1 = O_E1_3 + (e - 128); }
    const int sc2 = 0, st2 = 256, pb2 = O_E2_0 + e;
    int sc3, st3, pb3;
    if (e < 128) { sc3 = 0; st3 = 128; pb3 = O_E3_0 + e; }
    else         { sc3 = 1; st3 = 128; pb3 = O_E3_1 + (e - 128); }

    // ---------- chunk range for this block ----------
    const int nch = (n_nodes + CN - 1) / CN;
    const int c0  = (int)(((long long)blockIdx.x * nch) / NBLK);
    const int c1  = (int)(((long long)(blockIdx.x + 1) * nch) / NBLK);

    // ---------- staging helpers (reg-staged, T14 split) ----------
    auto stage_issue = [&](int c, fvec4& r0, fvec4& r1, fvec4& r2, fvec4& r3,
                           float& rs, int& ty, int& nv, int& total, int& cnn) {
        const long long cb = (long long)c * CN;
        cnn   = min(CN, (int)(n_nodes - cb));
        total = cnn * 14;
        nv    = total >> 2;
        const fvec4* vsrc = reinterpret_cast<const fvec4*>(x + cb * 14);
        if (tid < nv)          r0 = __builtin_nontemporal_load(vsrc + tid);
        if (tid + 512 < nv)    r1 = __builtin_nontemporal_load(vsrc + tid + 512);
        if (tid + 1024 < nv)   r2 = __builtin_nontemporal_load(vsrc + tid + 1024);
        if (tid + 1536 < nv)   r3 = __builtin_nontemporal_load(vsrc + tid + 1536);
        const int sf = (nv << 2) + tid;
        if (sf < total) rs = x[cb * 14 + sf];
        if (tid < cnn)  ty = node_types[cb + tid];
    };
    auto stage_write = [&](const fvec4& r0, const fvec4& r1, const fvec4& r2, const fvec4& r3,
                           float rs, int ty, int nv, int total, int cnn) {
        auto wr1 = [&](int i, const fvec4& v) {
            const int f = i << 2;
            int node = f / 14, col = f - node * 14;
            #pragma unroll
            for (int j = 0; j < 4; ++j) {
                smem[XSH + node * 16 + col] = v[j];
                if (++col == 14) { col = 0; ++node; }
            }
        };
        if (tid < nv)        wr1(tid, r0);
        if (tid + 512 < nv)  wr1(tid + 512, r1);
        if (tid + 1024 < nv) wr1(tid + 1024, r2);
        if (tid + 1536 < nv) wr1(tid + 1536, r3);
        const int sf = (nv << 2) + tid;
        if (sf < total) { const int node = sf / 14, col = sf - node * 14; smem[XSH + node * 16 + col] = rs; }
        if (tid < cnn) reinterpret_cast<int*>(&smem[TSH])[tid] = ty;
    };

    // ---------- compute one chunk (this thread's half) ----------
    auto do_chunk = [&](int c) {
        const long long cb = (long long)c * CN;
        const int cnn = min(CN, (int)(n_nodes - cb));
        const int nlo = h * 256;
        const int hn  = max(0, min(256, cnn - nlo));
        float* const outp = out + (cb + nlo) * 256 + e;
        const int* tsh = reinterpret_cast<const int*>(&smem[TSH]);

        auto gather = [&](int g) -> float {
            const int nl = nlo + g;
            const int t  = tsh[nl];
            const int sc = (t == 0) ? sc0 : (t == 1) ? sc1 : (t == 2) ? sc2 : sc3;
            const int st = (t == 0) ? st0 : (t == 1) ? st1 : (t == 2) ? st2 : st3;
            const int pb = (t == 0) ? pb0 : (t == 1) ? pb1 : (t == 2) ? pb2 : pb3;
            const int code = (int)smem[XSH + nl * 16 + sc];
            return smem[pb + code * st];
        };
        auto compute_node = [&](int g, float emb) {
            const int nl = nlo + g;
            const float* xr = &smem[XSH + nl * 16];
            const float4 ra = *reinterpret_cast<const float4*>(xr);      // cols 0..3
            const float4 rb = *reinterpret_cast<const float4*>(xr + 4);  // cols 4..7
            const float4 rc = *reinterpret_cast<const float4*>(xr + 8);  // cols 8..11
            const float2 rd = *reinterpret_cast<const float2*>(xr + 12); // cols 12..13
            const int t = tsh[nl];
            float acc;
            if (t == 0) {            // CONT0 = 0,1,4,6,7,8,9,10,11,12,13
                acc = fmaf(w0[0],  ra.x, bias0);
                acc = fmaf(w0[1],  ra.y, acc);
                acc = fmaf(w0[2],  rb.x, acc);
                acc = fmaf(w0[3],  rb.z, acc);
                acc = fmaf(w0[4],  rb.w, acc);
                acc = fmaf(w0[5],  rc.x, acc);
                acc = fmaf(w0[6],  rc.y, acc);
                acc = fmaf(w0[7],  rc.z, acc);
                acc = fmaf(w0[8],  rc.w, acc);
                acc = fmaf(w0[9],  rd.x, acc);
                acc = fmaf(w0[10], rd.y, acc);
            } else if (t == 1) {     // CONT1 = 0,1,4,5,6,7,8,9,10,11,12,13
                acc = fmaf(w1[0],  ra.x, bias1);
                acc = fmaf(w1[1],  ra.y, acc);
                acc = fmaf(w1[2],  rb.x, acc);
                acc = fmaf(w1[3],  rb.y, acc);
                acc = fmaf(w1[4],  rb.z, acc);
                acc = fmaf(w1[5],  rb.w, acc);
                acc = fmaf(w1[6],  rc.x, acc);
                acc = fmaf(w1[7],  rc.y, acc);
                acc = fmaf(w1[8],  rc.z, acc);
                acc = fmaf(w1[9],  rc.w, acc);
                acc = fmaf(w1[10], rd.x, acc);
                acc = fmaf(w1[11], rd.y, acc);
            } else if (t == 2) {     // CONT2 = 1,2,4,5,6,7,8,9,10,11,12,13
                acc = fmaf(w2[0],  ra.y, bias2);
                acc = fmaf(w2[1],  ra.z, acc);
                acc = fmaf(w2[2],  rb.x, acc);
                acc = fmaf(w2[3],  rb.y, acc);
                acc = fmaf(w2[4],  rb.z, acc);
                acc = fmaf(w2[5],  rb.w, acc);
                acc = fmaf(w2[6],  rc.x, acc);
                acc = fmaf(w2[7],  rc.y, acc);
                acc = fmaf(w2[8],  rc.z, acc);
                acc = fmaf(w2[9],  rc.w, acc);
                acc = fmaf(w2[10], rd.x, acc);
                acc = fmaf(w2[11], rd.y, acc);
            } else {                 // CONT3 = 2,3,4,5,6,7,8,9,10,11,12,13
                acc = fmaf(w3[0],  ra.z, bias3);
                acc = fmaf(w3[1],  ra.w, acc);
                acc = fmaf(w3[2],  rb.x, acc);
                acc = fmaf(w3[3],  rb.y, acc);
                acc = fmaf(w3[4],  rb.z, acc);
                acc = fmaf(w3[5],  rb.w, acc);
                acc = fmaf(w3[6],  rc.x, acc);
                acc = fmaf(w3[7],  rc.y, acc);
                acc = fmaf(w3[8],  rc.z, acc);
                acc = fmaf(w3[9],  rc.w, acc);
                acc = fmaf(w3[10], rd.x, acc);
                acc = fmaf(w3[11], rd.y, acc);
            }
            __builtin_nontemporal_store(acc + emb, outp + (size_t)g * 256);
        };

        // 8-deep pipelined gathers (now LDS -> lgkmcnt, decoupled from stores)
        float emb[8];
        #pragma unroll
        for (int j = 0; j < 8; ++j) emb[j] = (j < hn) ? gather(j) : 0.f;
        int base = 0;
        for (; base + 8 <= hn; base += 8) {
            float embN[8];
            #pragma unroll
            for (int j = 0; j < 8; ++j) {
                const int nn = base + 8 + j;
                embN[j] = (nn < hn) ? gather(nn) : 0.f;
            }
            #pragma unroll
            for (int j = 0; j < 8; ++j) compute_node(base + j, emb[j]);
            #pragma unroll
            for (int j = 0; j < 8; ++j) emb[j] = embN[j];
        }
        for (; base < hn; ++base) compute_node(base, gather(base));
    };

    // ---------- prologue: stage first chunk (tables copy still in flight) ----------
    {
        fvec4 r0, r1, r2, r3; float rs = 0.f; int ty = 0, nv = 0, total = 0, cnn = 0;
        if (c0 < c1) {
            stage_issue(c0, r0, r1, r2, r3, rs, ty, nv, total, cnn);
            stage_write(r0, r1, r2, r3, rs, ty, nv, total, cnn);
        }
    }
    __syncthreads();

    // ---------- main loop: compute chunk c while loading chunk c+1 ----------
    for (int c = c0; c < c1; ++c) {
        fvec4 r0, r1, r2, r3; float rs = 0.f; int ty = 0, nv = 0, total = 0, cnn = 0;
        const bool hasnext = (c + 1 < c1);
        if (hasnext) stage_issue(c + 1, r0, r1, r2, r3, rs, ty, nv, total, cnn);
        do_chunk(c);
        __syncthreads();                    // all reads of xsh/tsh done
        if (hasnext) stage_write(r0, r1, r2, r3, rs, ty, nv, total, cnn);
        __syncthreads();                    // staged chunk visible
    }
}

extern "C" void kernel_launch(void* const* d_in, const int* in_sizes, int n_in,
                              void* d_out, int out_size, void* d_ws, size_t ws_size,
                              hipStream_t stream) {
    // setup_inputs() dict order:
    //  0:x  1:node_types  2:W0 3:b0 4:E0_2 5:E0_3 6:E0_5
    //  7:W1 8:b1 9:E1_2 10:E1_3  11:W2 12:b2 13:E2_0  14:W3 15:b3 16:E3_0 17:E3_1
    const float* xp   = (const float*)d_in[0];
    const int*   ntp  = (const int*)d_in[1];
    const float* W0 = (const float*)d_in[2];
    const float* b0 = (const float*)d_in[3];
    const float* E0_2 = (const float*)d_in[4];
    const float* E0_3 = (const float*)d_in[5];
    const float* E0_5 = (const float*)d_in[6];
    const float* W1 = (const float*)d_in[7];
    const float* b1 = (const float*)d_in[8];
    const float* E1_2 = (const float*)d_in[9];
    const float* E1_3 = (const float*)d_in[10];
    const float* W2 = (const float*)d_in[11];
    const float* b2 = (const float*)d_in[12];
    const float* E2_0 = (const float*)d_in[13];
    const float* W3 = (const float*)d_in[14];
    const float* b3 = (const float*)d_in[15];
    const float* E3_0 = (const float*)d_in[16];
    const float* E3_1 = (const float*)d_in[17];
    float* outp = (float*)d_out;

    const int n_nodes = in_sizes[1];

    // Allow >64 KiB dynamic LDS (147.5 KiB; MI355X has 160 KiB/CU).
    // Host-side attribute set, not a stream op -> graph-capture safe.
    hipFuncSetAttribute(reinterpret_cast<const void*>(node_enc_kernel),
                        hipFuncAttributeMaxDynamicSharedMemorySize, SMEM_BYTES);

    node_enc_kernel<<<NBLK, TPB, SMEM_BYTES, stream>>>(
        xp, ntp, W0, b0, E0_2, E0_3, E0_5, W1, b1, E1_2, E1_3,
        W2, b2, E2_0, W3, b3, E3_0, E3_1, outp, n_nodes);
}

// Round 5
// 779.084 us; speedup vs baseline: 1.1657x; 1.1657x over previous
//
#include <hip/hip_runtime.h>

typedef float fvec4 __attribute__((ext_vector_type(4)));

#define NBLK 256
#define TPB  1024
#define CN   512            // nodes per chunk

// ---- LDS layout (float offsets) ----
#define O_E0_2 0            // 96*86  = 8256
#define O_E0_3 8256         // 8*85   = 680
#define O_E0_5 8936         // 2*85   = 170  (pad 2)
#define O_E1_2 9108         // 4*128  = 512
#define O_E1_3 9620         // 22*128 = 2816
#define O_E2_0 12436        // 6*256  = 1536
#define O_E3_0 13972        // 15*128 = 1920
#define O_E3_1 15892        // 96*128 = 12288
#define NTAB   28180
#define XSH    NTAB                 // CN*16 floats (rows padded 14->16)
#define TSH    (XSH + CN * 16)      // CN ints
#define SMEM_FLOATS (TSH + CN)      // 36884
#define SMEM_BYTES  (SMEM_FLOATS * 4)   // 147536 B < 160 KiB

extern __shared__ float smem[];

__global__ __launch_bounds__(TPB, 1)
void node_enc_kernel(const float* __restrict__ x,
                     const int* __restrict__ node_types,
                     const float* __restrict__ W0, const float* __restrict__ b0,
                     const float* __restrict__ E0_2, const float* __restrict__ E0_3,
                     const float* __restrict__ E0_5,
                     const float* __restrict__ W1, const float* __restrict__ b1,
                     const float* __restrict__ E1_2, const float* __restrict__ E1_3,
                     const float* __restrict__ W2, const float* __restrict__ b2,
                     const float* __restrict__ E2_0,
                     const float* __restrict__ W3, const float* __restrict__ b3,
                     const float* __restrict__ E3_0, const float* __restrict__ E3_1,
                     float* __restrict__ out, int n_nodes)
{
    const int tid = threadIdx.x;
    const int e   = tid & 255;   // output column owned by this thread
    const int h   = tid >> 8;    // which 128-node quarter of the chunk (0..3)

    // ---------- copy all embedding tables into LDS (once per block) ----------
    auto copy_tab = [&](const float* __restrict__ src, int dst, int n) {
        if ((((uintptr_t)src) & 15) == 0) {
            const int nv = n >> 2;
            for (int i = tid; i < nv; i += TPB) {
                const fvec4 v = *(reinterpret_cast<const fvec4*>(src) + i);
                *reinterpret_cast<fvec4*>(&smem[dst + (i << 2)]) = v;
            }
            for (int i = (nv << 2) + tid; i < n; i += TPB) smem[dst + i] = src[i];
        } else {
            for (int i = tid; i < n; i += TPB) smem[dst + i] = src[i];
        }
    };
    copy_tab(E0_2, O_E0_2, 8256);
    copy_tab(E0_3, O_E0_3, 680);
    copy_tab(E0_5, O_E0_5, 170);
    copy_tab(E1_2, O_E1_2, 512);
    copy_tab(E1_3, O_E1_3, 2816);
    copy_tab(E2_0, O_E2_0, 1536);
    copy_tab(E3_0, O_E3_0, 1920);
    copy_tab(E3_1, O_E3_1, 12288);

    // ---------- per-column weights for all 4 types -> registers ----------
    float w0[11], w1[12], w2[12], w3[12];
    #pragma unroll
    for (int k = 0; k < 11; ++k) w0[k] = W0[e * 11 + k];
    #pragma unroll
    for (int k = 0; k < 12; ++k) w1[k] = W1[e * 12 + k];
    #pragma unroll
    for (int k = 0; k < 12; ++k) w2[k] = W2[e * 12 + k];
    #pragma unroll
    for (int k = 0; k < 12; ++k) w3[k] = W3[e * 12 + k];
    const float bias0 = b0[e], bias1 = b1[e], bias2 = b2[e], bias3 = b3[e];

    // ---------- per-thread embedding descriptors (LDS float offsets) ----------
    int sc0, st0, pb0;
    if (e < 86)       { sc0 = 2; st0 = 86; pb0 = O_E0_2 + e; }
    else if (e < 171) { sc0 = 3; st0 = 85; pb0 = O_E0_3 + (e - 86); }
    else              { sc0 = 5; st0 = 85; pb0 = O_E0_5 + (e - 171); }
    int sc1, st1, pb1;
    if (e < 128) { sc1 = 2; st1 = 128; pb1 = O_E1_2 + e; }
    else         { sc1 = 3; st1 = 128; pb1 = O_E1_3 + (e - 128); }
    const int sc2 = 0, st2 = 256, pb2 = O_E2_0 + e;
    int sc3, st3, pb3;
    if (e < 128) { sc3 = 0; st3 = 128; pb3 = O_E3_0 + e; }
    else         { sc3 = 1; st3 = 128; pb3 = O_E3_1 + (e - 128); }

    // ---------- chunk range for this block ----------
    const int nch = (n_nodes + CN - 1) / CN;
    const int c0  = (int)(((long long)blockIdx.x * nch) / NBLK);
    const int c1  = (int)(((long long)(blockIdx.x + 1) * nch) / NBLK);

    // ---------- staging helpers (reg-staged, issue-early / write-late) ----------
    auto stage_issue = [&](int c, fvec4& r0, fvec4& r1,
                           float& rs, int& ty, int& nv, int& total, int& cnn) {
        const long long cb = (long long)c * CN;
        cnn   = min(CN, (int)(n_nodes - cb));
        total = cnn * 14;
        nv    = total >> 2;            // max 1792 (< 2*TPB)
        const fvec4* vsrc = reinterpret_cast<const fvec4*>(x + cb * 14);
        if (tid < nv)          r0 = __builtin_nontemporal_load(vsrc + tid);
        if (tid + TPB < nv)    r1 = __builtin_nontemporal_load(vsrc + tid + TPB);
        const int sf = (nv << 2) + tid;
        if (sf < total) rs = x[cb * 14 + sf];
        if (tid < cnn)  ty = node_types[cb + tid];
    };
    auto stage_write = [&](const fvec4& r0, const fvec4& r1,
                           float rs, int ty, int nv, int total, int cnn) {
        auto wr1 = [&](int i, const fvec4& v) {
            const int f = i << 2;
            int node = f / 14, col = f - node * 14;
            #pragma unroll
            for (int j = 0; j < 4; ++j) {
                smem[XSH + node * 16 + col] = v[j];
                if (++col == 14) { col = 0; ++node; }
            }
        };
        if (tid < nv)        wr1(tid, r0);
        if (tid + TPB < nv)  wr1(tid + TPB, r1);
        const int sf = (nv << 2) + tid;
        if (sf < total) { const int node = sf / 14, col = sf - node * 14; smem[XSH + node * 16 + col] = rs; }
        if (tid < cnn) reinterpret_cast<int*>(&smem[TSH])[tid] = ty;
    };

    // ---------- compute one chunk (this thread's quarter) ----------
    auto do_chunk = [&](int c) {
        const long long cb = (long long)c * CN;
        const int cnn = min(CN, (int)(n_nodes - cb));
        const int nlo = h * 128;
        const int hn  = max(0, min(128, cnn - nlo));
        float* const outp = out + (cb + nlo) * 256 + e;
        const int* tsh = reinterpret_cast<const int*>(&smem[TSH]);

        auto gather = [&](int g) -> float {
            const int nl = nlo + g;
            const int t  = tsh[nl];
            const int sc = (t == 0) ? sc0 : (t == 1) ? sc1 : (t == 2) ? sc2 : sc3;
            const int st = (t == 0) ? st0 : (t == 1) ? st1 : (t == 2) ? st2 : st3;
            const int pb = (t == 0) ? pb0 : (t == 1) ? pb1 : (t == 2) ? pb2 : pb3;
            const int code = (int)smem[XSH + nl * 16 + sc];
            return smem[pb + code * st];
        };
        auto compute_node = [&](int g, float emb) {
            const int nl = nlo + g;
            const float* xr = &smem[XSH + nl * 16];
            const float4 ra = *reinterpret_cast<const float4*>(xr);      // cols 0..3
            const float4 rb = *reinterpret_cast<const float4*>(xr + 4);  // cols 4..7
            const float4 rc = *reinterpret_cast<const float4*>(xr + 8);  // cols 8..11
            const float2 rd = *reinterpret_cast<const float2*>(xr + 12); // cols 12..13
            const int t = tsh[nl];
            float acc;
            if (t == 0) {            // CONT0 = 0,1,4,6,7,8,9,10,11,12,13
                acc = fmaf(w0[0],  ra.x, bias0);
                acc = fmaf(w0[1],  ra.y, acc);
                acc = fmaf(w0[2],  rb.x, acc);
                acc = fmaf(w0[3],  rb.z, acc);
                acc = fmaf(w0[4],  rb.w, acc);
                acc = fmaf(w0[5],  rc.x, acc);
                acc = fmaf(w0[6],  rc.y, acc);
                acc = fmaf(w0[7],  rc.z, acc);
                acc = fmaf(w0[8],  rc.w, acc);
                acc = fmaf(w0[9],  rd.x, acc);
                acc = fmaf(w0[10], rd.y, acc);
            } else if (t == 1) {     // CONT1 = 0,1,4,5,6,7,8,9,10,11,12,13
                acc = fmaf(w1[0],  ra.x, bias1);
                acc = fmaf(w1[1],  ra.y, acc);
                acc = fmaf(w1[2],  rb.x, acc);
                acc = fmaf(w1[3],  rb.y, acc);
                acc = fmaf(w1[4],  rb.z, acc);
                acc = fmaf(w1[5],  rb.w, acc);
                acc = fmaf(w1[6],  rc.x, acc);
                acc = fmaf(w1[7],  rc.y, acc);
                acc = fmaf(w1[8],  rc.z, acc);
                acc = fmaf(w1[9],  rc.w, acc);
                acc = fmaf(w1[10], rd.x, acc);
                acc = fmaf(w1[11], rd.y, acc);
            } else if (t == 2) {     // CONT2 = 1,2,4,5,6,7,8,9,10,11,12,13
                acc = fmaf(w2[0],  ra.y, bias2);
                acc = fmaf(w2[1],  ra.z, acc);
                acc = fmaf(w2[2],  rb.x, acc);
                acc = fmaf(w2[3],  rb.y, acc);
                acc = fmaf(w2[4],  rb.z, acc);
                acc = fmaf(w2[5],  rb.w, acc);
                acc = fmaf(w2[6],  rc.x, acc);
                acc = fmaf(w2[7],  rc.y, acc);
                acc = fmaf(w2[8],  rc.z, acc);
                acc = fmaf(w2[9],  rc.w, acc);
                acc = fmaf(w2[10], rd.x, acc);
                acc = fmaf(w2[11], rd.y, acc);
            } else {                 // CONT3 = 2,3,4,5,6,7,8,9,10,11,12,13
                acc = fmaf(w3[0],  ra.z, bias3);
                acc = fmaf(w3[1],  ra.w, acc);
                acc = fmaf(w3[2],  rb.x, acc);
                acc = fmaf(w3[3],  rb.y, acc);
                acc = fmaf(w3[4],  rb.z, acc);
                acc = fmaf(w3[5],  rb.w, acc);
                acc = fmaf(w3[6],  rc.x, acc);
                acc = fmaf(w3[7],  rc.y, acc);
                acc = fmaf(w3[8],  rc.z, acc);
                acc = fmaf(w3[9],  rc.w, acc);
                acc = fmaf(w3[10], rd.x, acc);
                acc = fmaf(w3[11], rd.y, acc);
            }
            // plain cached store: acks at L2 (~200cy), L2 write-back streams to HBM.
            outp[(size_t)g * 256] = acc + emb;
        };

        // 8-deep pipelined gathers (LDS)
        float emb[8];
        #pragma unroll
        for (int j = 0; j < 8; ++j) emb[j] = (j < hn) ? gather(j) : 0.f;
        int base = 0;
        for (; base + 8 <= hn; base += 8) {
            float embN[8];
            #pragma unroll
            for (int j = 0; j < 8; ++j) {
                const int nn = base + 8 + j;
                embN[j] = (nn < hn) ? gather(nn) : 0.f;
            }
            #pragma unroll
            for (int j = 0; j < 8; ++j) compute_node(base + j, emb[j]);
            #pragma unroll
            for (int j = 0; j < 8; ++j) emb[j] = embN[j];
        }
        for (; base < hn; ++base) compute_node(base, gather(base));
    };

    // ---------- prologue: stage first chunk ----------
    {
        fvec4 r0, r1; float rs = 0.f; int ty = 0, nv = 0, total = 0, cnn = 0;
        if (c0 < c1) {
            stage_issue(c0, r0, r1, rs, ty, nv, total, cnn);
            stage_write(r0, r1, rs, ty, nv, total, cnn);
        }
    }
    __syncthreads();

    // ---------- main loop: compute chunk c while loading chunk c+1 ----------
    for (int c = c0; c < c1; ++c) {
        fvec4 r0, r1; float rs = 0.f; int ty = 0, nv = 0, total = 0, cnn = 0;
        const bool hasnext = (c + 1 < c1);
        if (hasnext) stage_issue(c + 1, r0, r1, rs, ty, nv, total, cnn);
        do_chunk(c);
        __syncthreads();                    // all reads of xsh/tsh done
        if (hasnext) stage_write(r0, r1, rs, ty, nv, total, cnn);
        __syncthreads();                    // staged chunk visible
    }
}

extern "C" void kernel_launch(void* const* d_in, const int* in_sizes, int n_in,
                              void* d_out, int out_size, void* d_ws, size_t ws_size,
                              hipStream_t stream) {
    // setup_inputs() dict order:
    //  0:x  1:node_types  2:W0 3:b0 4:E0_2 5:E0_3 6:E0_5
    //  7:W1 8:b1 9:E1_2 10:E1_3  11:W2 12:b2 13:E2_0  14:W3 15:b3 16:E3_0 17:E3_1
    const float* xp   = (const float*)d_in[0];
    const int*   ntp  = (const int*)d_in[1];
    const float* W0 = (const float*)d_in[2];
    const float* b0 = (const float*)d_in[3];
    const float* E0_2 = (const float*)d_in[4];
    const float* E0_3 = (const float*)d_in[5];
    const float* E0_5 = (const float*)d_in[6];
    const float* W1 = (const float*)d_in[7];
    const float* b1 = (const float*)d_in[8];
    const float* E1_2 = (const float*)d_in[9];
    const float* E1_3 = (const float*)d_in[10];
    const float* W2 = (const float*)d_in[11];
    const float* b2 = (const float*)d_in[12];
    const float* E2_0 = (const float*)d_in[13];
    const float* W3 = (const float*)d_in[14];
    const float* b3 = (const float*)d_in[15];
    const float* E3_0 = (const float*)d_in[16];
    const float* E3_1 = (const float*)d_in[17];
    float* outp = (float*)d_out;

    const int n_nodes = in_sizes[1];

    hipFuncSetAttribute(reinterpret_cast<const void*>(node_enc_kernel),
                        hipFuncAttributeMaxDynamicSharedMemorySize, SMEM_BYTES);

    node_enc_kernel<<<NBLK, TPB, SMEM_BYTES, stream>>>(
        xp, ntp, W0, b0, E0_2, E0_3, E0_5, W1, b1, E1_2, E1_3,
        W2, b2, E2_0, W3, b3, E3_0, E3_1, outp, n_nodes);
}

// Round 6
// 777.208 us; speedup vs baseline: 1.1686x; 1.0024x over previous
//
#include <hip/hip_runtime.h>

typedef float fvec4 __attribute__((ext_vector_type(4)));

#define NBLK 256
#define TPB  1024
#define CN   512            // nodes per chunk

// Force a value to stay materialized in a VGPR (prevents the compiler from
// re-loading loop-invariant weights from global memory every iteration).
#define KEEP(x) asm volatile("" : "+v"(x))

// ---- LDS layout (float offsets) ----
#define O_E0_2 0            // 96*86  = 8256
#define O_E0_3 8256         // 8*85   = 680
#define O_E0_5 8936         // 2*85   = 170  (pad 2)
#define O_E1_2 9108         // 4*128  = 512
#define O_E1_3 9620         // 22*128 = 2816
#define O_E2_0 12436        // 6*256  = 1536
#define O_E3_0 13972        // 15*128 = 1920
#define O_E3_1 15892        // 96*128 = 12288
#define NTAB   28180
#define XSH    NTAB                 // CN*16 floats (rows padded 14->16)
#define TSH    (XSH + CN * 16)      // CN ints
#define SMEM_FLOATS (TSH + CN)      // 36884
#define SMEM_BYTES  (SMEM_FLOATS * 4)   // 147536 B < 160 KiB

extern __shared__ float smem[];

__global__ __launch_bounds__(TPB, 1)
void node_enc_kernel(const float* __restrict__ x,
                     const int* __restrict__ node_types,
                     const float* __restrict__ W0, const float* __restrict__ b0,
                     const float* __restrict__ E0_2, const float* __restrict__ E0_3,
                     const float* __restrict__ E0_5,
                     const float* __restrict__ W1, const float* __restrict__ b1,
                     const float* __restrict__ E1_2, const float* __restrict__ E1_3,
                     const float* __restrict__ W2, const float* __restrict__ b2,
                     const float* __restrict__ E2_0,
                     const float* __restrict__ W3, const float* __restrict__ b3,
                     const float* __restrict__ E3_0, const float* __restrict__ E3_1,
                     float* __restrict__ out, int n_nodes)
{
    const int tid = threadIdx.x;
    const int e   = tid & 255;   // output column owned by this thread
    const int h   = tid >> 8;    // which 128-node quarter of the chunk (0..3)

    // ---------- copy all embedding tables into LDS (once per block) ----------
    auto copy_tab = [&](const float* __restrict__ src, int dst, int n) {
        if ((((uintptr_t)src) & 15) == 0) {
            const int nv = n >> 2;
            for (int i = tid; i < nv; i += TPB) {
                const fvec4 v = *(reinterpret_cast<const fvec4*>(src) + i);
                *reinterpret_cast<fvec4*>(&smem[dst + (i << 2)]) = v;
            }
            for (int i = (nv << 2) + tid; i < n; i += TPB) smem[dst + i] = src[i];
        } else {
            for (int i = tid; i < n; i += TPB) smem[dst + i] = src[i];
        }
    };
    copy_tab(E0_2, O_E0_2, 8256);
    copy_tab(E0_3, O_E0_3, 680);
    copy_tab(E0_5, O_E0_5, 170);
    copy_tab(E1_2, O_E1_2, 512);
    copy_tab(E1_3, O_E1_3, 2816);
    copy_tab(E2_0, O_E2_0, 1536);
    copy_tab(E3_0, O_E3_0, 1920);
    copy_tab(E3_1, O_E3_1, 12288);

    // ---------- per-column weights for all 4 types -> registers (PINNED) ----------
    float w0[11], w1[12], w2[12], w3[12];
    #pragma unroll
    for (int k = 0; k < 11; ++k) w0[k] = W0[e * 11 + k];
    #pragma unroll
    for (int k = 0; k < 12; ++k) w1[k] = W1[e * 12 + k];
    #pragma unroll
    for (int k = 0; k < 12; ++k) w2[k] = W2[e * 12 + k];
    #pragma unroll
    for (int k = 0; k < 12; ++k) w3[k] = W3[e * 12 + k];
    float bias0 = b0[e], bias1 = b1[e], bias2 = b2[e], bias3 = b3[e];

    // Pin everything loop-invariant into VGPRs: the compiler must not
    // rematerialize these from memory inside the hot loop.
    #pragma unroll
    for (int k = 0; k < 11; ++k) KEEP(w0[k]);
    #pragma unroll
    for (int k = 0; k < 12; ++k) KEEP(w1[k]);
    #pragma unroll
    for (int k = 0; k < 12; ++k) KEEP(w2[k]);
    #pragma unroll
    for (int k = 0; k < 12; ++k) KEEP(w3[k]);
    KEEP(bias0); KEEP(bias1); KEEP(bias2); KEEP(bias3);

    // ---------- per-thread embedding descriptors (LDS float offsets) ----------
    int sc0, st0, pb0;
    if (e < 86)       { sc0 = 2; st0 = 86; pb0 = O_E0_2 + e; }
    else if (e < 171) { sc0 = 3; st0 = 85; pb0 = O_E0_3 + (e - 86); }
    else              { sc0 = 5; st0 = 85; pb0 = O_E0_5 + (e - 171); }
    int sc1, st1, pb1;
    if (e < 128) { sc1 = 2; st1 = 128; pb1 = O_E1_2 + e; }
    else         { sc1 = 3; st1 = 128; pb1 = O_E1_3 + (e - 128); }
    const int sc2 = 0, st2 = 256, pb2 = O_E2_0 + e;
    int sc3, st3, pb3;
    if (e < 128) { sc3 = 0; st3 = 128; pb3 = O_E3_0 + e; }
    else         { sc3 = 1; st3 = 128; pb3 = O_E3_1 + (e - 128); }

    // ---------- chunk range for this block ----------
    const int nch = (n_nodes + CN - 1) / CN;
    const int c0  = (int)(((long long)blockIdx.x * nch) / NBLK);
    const int c1  = (int)(((long long)(blockIdx.x + 1) * nch) / NBLK);

    // ---------- staging helpers (reg-staged, issue-early / write-late) ----------
    auto stage_issue = [&](int c, fvec4& r0, fvec4& r1,
                           float& rs, int& ty, int& nv, int& total, int& cnn) {
        const long long cb = (long long)c * CN;
        cnn   = min(CN, (int)(n_nodes - cb));
        total = cnn * 14;
        nv    = total >> 2;            // max 1792 (< 2*TPB)
        const fvec4* vsrc = reinterpret_cast<const fvec4*>(x + cb * 14);
        if (tid < nv)          r0 = __builtin_nontemporal_load(vsrc + tid);
        if (tid + TPB < nv)    r1 = __builtin_nontemporal_load(vsrc + tid + TPB);
        const int sf = (nv << 2) + tid;
        if (sf < total) rs = x[cb * 14 + sf];
        if (tid < cnn)  ty = node_types[cb + tid];
    };
    auto stage_write = [&](const fvec4& r0, const fvec4& r1,
                           float rs, int ty, int nv, int total, int cnn) {
        auto wr1 = [&](int i, const fvec4& v) {
            const int f = i << 2;
            int node = f / 14, col = f - node * 14;
            #pragma unroll
            for (int j = 0; j < 4; ++j) {
                smem[XSH + node * 16 + col] = v[j];
                if (++col == 14) { col = 0; ++node; }
            }
        };
        if (tid < nv)        wr1(tid, r0);
        if (tid + TPB < nv)  wr1(tid + TPB, r1);
        const int sf = (nv << 2) + tid;
        if (sf < total) { const int node = sf / 14, col = sf - node * 14; smem[XSH + node * 16 + col] = rs; }
        if (tid < cnn) reinterpret_cast<int*>(&smem[TSH])[tid] = ty;
    };

    // ---------- compute one chunk (this thread's quarter) ----------
    auto do_chunk = [&](int c) {
        const long long cb = (long long)c * CN;
        const int cnn = min(CN, (int)(n_nodes - cb));
        const int nlo = h * 128;
        const int hn  = max(0, min(128, cnn - nlo));
        float* const outp = out + (cb + nlo) * 256 + e;
        const int* tsh = reinterpret_cast<const int*>(&smem[TSH]);

        auto gather = [&](int g) -> float {
            const int nl = nlo + g;
            const int t  = tsh[nl];
            const int sc = (t == 0) ? sc0 : (t == 1) ? sc1 : (t == 2) ? sc2 : sc3;
            const int st = (t == 0) ? st0 : (t == 1) ? st1 : (t == 2) ? st2 : st3;
            const int pb = (t == 0) ? pb0 : (t == 1) ? pb1 : (t == 2) ? pb2 : pb3;
            const int code = (int)smem[XSH + nl * 16 + sc];
            return smem[pb + code * st];
        };
        auto compute_node = [&](int g, float emb) {
            const int nl = nlo + g;
            const float* xr = &smem[XSH + nl * 16];
            const float4 ra = *reinterpret_cast<const float4*>(xr);      // cols 0..3
            const float4 rb = *reinterpret_cast<const float4*>(xr + 4);  // cols 4..7
            const float4 rc = *reinterpret_cast<const float4*>(xr + 8);  // cols 8..11
            const float2 rd = *reinterpret_cast<const float2*>(xr + 12); // cols 12..13
            const int t = tsh[nl];
            float acc;
            if (t == 0) {            // CONT0 = 0,1,4,6,7,8,9,10,11,12,13
                acc = fmaf(w0[0],  ra.x, bias0);
                acc = fmaf(w0[1],  ra.y, acc);
                acc = fmaf(w0[2],  rb.x, acc);
                acc = fmaf(w0[3],  rb.z, acc);
                acc = fmaf(w0[4],  rb.w, acc);
                acc = fmaf(w0[5],  rc.x, acc);
                acc = fmaf(w0[6],  rc.y, acc);
                acc = fmaf(w0[7],  rc.z, acc);
                acc = fmaf(w0[8],  rc.w, acc);
                acc = fmaf(w0[9],  rd.x, acc);
                acc = fmaf(w0[10], rd.y, acc);
            } else if (t == 1) {     // CONT1 = 0,1,4,5,6,7,8,9,10,11,12,13
                acc = fmaf(w1[0],  ra.x, bias1);
                acc = fmaf(w1[1],  ra.y, acc);
                acc = fmaf(w1[2],  rb.x, acc);
                acc = fmaf(w1[3],  rb.y, acc);
                acc = fmaf(w1[4],  rb.z, acc);
                acc = fmaf(w1[5],  rb.w, acc);
                acc = fmaf(w1[6],  rc.x, acc);
                acc = fmaf(w1[7],  rc.y, acc);
                acc = fmaf(w1[8],  rc.z, acc);
                acc = fmaf(w1[9],  rc.w, acc);
                acc = fmaf(w1[10], rd.x, acc);
                acc = fmaf(w1[11], rd.y, acc);
            } else if (t == 2) {     // CONT2 = 1,2,4,5,6,7,8,9,10,11,12,13
                acc = fmaf(w2[0],  ra.y, bias2);
                acc = fmaf(w2[1],  ra.z, acc);
                acc = fmaf(w2[2],  rb.x, acc);
                acc = fmaf(w2[3],  rb.y, acc);
                acc = fmaf(w2[4],  rb.z, acc);
                acc = fmaf(w2[5],  rb.w, acc);
                acc = fmaf(w2[6],  rc.x, acc);
                acc = fmaf(w2[7],  rc.y, acc);
                acc = fmaf(w2[8],  rc.z, acc);
                acc = fmaf(w2[9],  rc.w, acc);
                acc = fmaf(w2[10], rd.x, acc);
                acc = fmaf(w2[11], rd.y, acc);
            } else {                 // CONT3 = 2,3,4,5,6,7,8,9,10,11,12,13
                acc = fmaf(w3[0],  ra.z, bias3);
                acc = fmaf(w3[1],  ra.w, acc);
                acc = fmaf(w3[2],  rb.x, acc);
                acc = fmaf(w3[3],  rb.y, acc);
                acc = fmaf(w3[4],  rb.z, acc);
                acc = fmaf(w3[5],  rb.w, acc);
                acc = fmaf(w3[6],  rc.x, acc);
                acc = fmaf(w3[7],  rc.y, acc);
                acc = fmaf(w3[8],  rc.z, acc);
                acc = fmaf(w3[9],  rc.w, acc);
                acc = fmaf(w3[10], rd.x, acc);
                acc = fmaf(w3[11], rd.y, acc);
            }
            outp[(size_t)g * 256] = acc + emb;
        };

        // 4-deep pipelined gathers (LDS latency ~120cy; 4 is ample cover)
        float emb[4];
        #pragma unroll
        for (int j = 0; j < 4; ++j) emb[j] = (j < hn) ? gather(j) : 0.f;
        int base = 0;
        for (; base + 4 <= hn; base += 4) {
            float embN[4];
            #pragma unroll
            for (int j = 0; j < 4; ++j) {
                const int nn = base + 4 + j;
                embN[j] = (nn < hn) ? gather(nn) : 0.f;
            }
            #pragma unroll
            for (int j = 0; j < 4; ++j) compute_node(base + j, emb[j]);
            #pragma unroll
            for (int j = 0; j < 4; ++j) emb[j] = embN[j];
        }
        for (; base < hn; ++base) compute_node(base, gather(base));
    };

    // ---------- prologue: stage first chunk ----------
    {
        fvec4 r0, r1; float rs = 0.f; int ty = 0, nv = 0, total = 0, cnn = 0;
        if (c0 < c1) {
            stage_issue(c0, r0, r1, rs, ty, nv, total, cnn);
            stage_write(r0, r1, rs, ty, nv, total, cnn);
        }
    }
    __syncthreads();

    // ---------- main loop: compute chunk c while loading chunk c+1 ----------
    for (int c = c0; c < c1; ++c) {
        fvec4 r0, r1; float rs = 0.f; int ty = 0, nv = 0, total = 0, cnn = 0;
        const bool hasnext = (c + 1 < c1);
        if (hasnext) stage_issue(c + 1, r0, r1, rs, ty, nv, total, cnn);
        do_chunk(c);
        __syncthreads();                    // all reads of xsh/tsh done
        if (hasnext) stage_write(r0, r1, rs, ty, nv, total, cnn);
        __syncthreads();                    // staged chunk visible
    }
}

extern "C" void kernel_launch(void* const* d_in, const int* in_sizes, int n_in,
                              void* d_out, int out_size, void* d_ws, size_t ws_size,
                              hipStream_t stream) {
    // setup_inputs() dict order:
    //  0:x  1:node_types  2:W0 3:b0 4:E0_2 5:E0_3 6:E0_5
    //  7:W1 8:b1 9:E1_2 10:E1_3  11:W2 12:b2 13:E2_0  14:W3 15:b3 16:E3_0 17:E3_1
    const float* xp   = (const float*)d_in[0];
    const int*   ntp  = (const int*)d_in[1];
    const float* W0 = (const float*)d_in[2];
    const float* b0 = (const float*)d_in[3];
    const float* E0_2 = (const float*)d_in[4];
    const float* E0_3 = (const float*)d_in[5];
    const float* E0_5 = (const float*)d_in[6];
    const float* W1 = (const float*)d_in[7];
    const float* b1 = (const float*)d_in[8];
    const float* E1_2 = (const float*)d_in[9];
    const float* E1_3 = (const float*)d_in[10];
    const float* W2 = (const float*)d_in[11];
    const float* b2 = (const float*)d_in[12];
    const float* E2_0 = (const float*)d_in[13];
    const float* W3 = (const float*)d_in[14];
    const float* b3 = (const float*)d_in[15];
    const float* E3_0 = (const float*)d_in[16];
    const float* E3_1 = (const float*)d_in[17];
    float* outp = (float*)d_out;

    const int n_nodes = in_sizes[1];

    hipFuncSetAttribute(reinterpret_cast<const void*>(node_enc_kernel),
                        hipFuncAttributeMaxDynamicSharedMemorySize, SMEM_BYTES);

    node_enc_kernel<<<NBLK, TPB, SMEM_BYTES, stream>>>(
        xp, ntp, W0, b0, E0_2, E0_3, E0_5, W1, b1, E1_2, E1_3,
        W2, b2, E2_0, W3, b3, E3_0, E3_1, outp, n_nodes);
}

// Round 7
// 155.950 us; speedup vs baseline: 5.8237x; 4.9837x over previous
//
#include <hip/hip_runtime.h>

typedef float fvec4 __attribute__((ext_vector_type(4)));

#define NBLK 256
#define TPB  1024
#define CN   512            // nodes per chunk

// Defeat LICM: make a pointer opaque so invariant loads through it cannot be
// hoisted out of the chunk loop (which would make 51 weights live at once ->
// guaranteed spill, the R2-R6 disease).
#define LAUNDER_PTR(p) asm volatile("" : "+v"(p))

// ---- LDS layout (float offsets) ----
#define O_E0_2 0            // 96*86  = 8256
#define O_E0_3 8256         // 8*85   = 680
#define O_E0_5 8936         // 2*85   = 170  (pad 2)
#define O_E1_2 9108         // 4*128  = 512
#define O_E1_3 9620         // 22*128 = 2816
#define O_E2_0 12436        // 6*256  = 1536
#define O_E3_0 13972        // 15*128 = 1920
#define O_E3_1 15892        // 96*128 = 12288
#define NTAB   28180
#define XSH    NTAB                 // CN*16 floats (rows padded 14->16)
#define IDX    (XSH + CN * 16)      // 4*CN ints: per-type node index lists
#define CNTO   (IDX + 4 * CN)       // 4 ints: per-type counts
#define SMEM_FLOATS (CNTO + 4)      // 38424
#define SMEM_BYTES  (SMEM_FLOATS * 4)   // 153696 B < 160 KiB

extern __shared__ float smem[];

// One type-specialized node loop. Only ~13 weights live inside; no global
// loads in the g-loop (LDS reads + one store only).
#define TYPE_BLOCK(T, NW, WPTR, BPTR, SC, ST, PB, ...)                         \
  {                                                                            \
    const int m = cnt_ro[T];                                                   \
    const float* Wp = WPTR; LAUNDER_PTR(Wp);                                   \
    const float* bp = BPTR; LAUNDER_PTR(bp);                                   \
    float w[NW];                                                               \
    _Pragma("unroll")                                                          \
    for (int k = 0; k < NW; ++k) w[k] = Wp[e * NW + k];                        \
    const float bias = bp[e];                                                  \
    for (int g = h; g < m; g += 4) {                                           \
      const int nl = idx_ro[T * CN + g];                                       \
      const float* xr = &smem[XSH + nl * 16];                                  \
      const float4 ra = *reinterpret_cast<const float4*>(xr);                  \
      const float4 rb = *reinterpret_cast<const float4*>(xr + 4);              \
      const float4 rc = *reinterpret_cast<const float4*>(xr + 8);              \
      const float2 rd = *reinterpret_cast<const float2*>(xr + 12);             \
      const int code = (int)xr[SC];                                            \
      const float emb = smem[(PB) + code * (ST)];                              \
      float acc = bias;                                                        \
      __VA_ARGS__                                                              \
      out[(cb + nl) * 256 + e] = acc + emb;                                    \
    }                                                                          \
  }

__global__ __launch_bounds__(TPB, 1)
void node_enc_kernel(const float* __restrict__ x,
                     const int* __restrict__ node_types,
                     const float* __restrict__ W0, const float* __restrict__ b0,
                     const float* __restrict__ E0_2, const float* __restrict__ E0_3,
                     const float* __restrict__ E0_5,
                     const float* __restrict__ W1, const float* __restrict__ b1,
                     const float* __restrict__ E1_2, const float* __restrict__ E1_3,
                     const float* __restrict__ W2, const float* __restrict__ b2,
                     const float* __restrict__ E2_0,
                     const float* __restrict__ W3, const float* __restrict__ b3,
                     const float* __restrict__ E3_0, const float* __restrict__ E3_1,
                     float* __restrict__ out, int n_nodes)
{
    const int tid = threadIdx.x;
    const int e   = tid & 255;   // output column owned by this thread
    const int h   = tid >> 8;    // node-interleave group (0..3)

    // ---------- copy all embedding tables into LDS (once per block) ----------
    auto copy_tab = [&](const float* __restrict__ src, int dst, int n) {
        if ((((uintptr_t)src) & 15) == 0) {
            const int nv = n >> 2;
            for (int i = tid; i < nv; i += TPB) {
                const fvec4 v = *(reinterpret_cast<const fvec4*>(src) + i);
                *reinterpret_cast<fvec4*>(&smem[dst + (i << 2)]) = v;
            }
            for (int i = (nv << 2) + tid; i < n; i += TPB) smem[dst + i] = src[i];
        } else {
            for (int i = tid; i < n; i += TPB) smem[dst + i] = src[i];
        }
    };
    copy_tab(E0_2, O_E0_2, 8256);
    copy_tab(E0_3, O_E0_3, 680);
    copy_tab(E0_5, O_E0_5, 170);
    copy_tab(E1_2, O_E1_2, 512);
    copy_tab(E1_3, O_E1_3, 2816);
    copy_tab(E2_0, O_E2_0, 1536);
    copy_tab(E3_0, O_E3_0, 1920);
    copy_tab(E3_1, O_E3_1, 12288);

    // ---------- per-thread embedding descriptors (LDS float offsets) ----------
    int sc0, st0, pb0;
    if (e < 86)       { sc0 = 2; st0 = 86; pb0 = O_E0_2 + e; }
    else if (e < 171) { sc0 = 3; st0 = 85; pb0 = O_E0_3 + (e - 86); }
    else              { sc0 = 5; st0 = 85; pb0 = O_E0_5 + (e - 171); }
    int sc1, st1, pb1;
    if (e < 128) { sc1 = 2; st1 = 128; pb1 = O_E1_2 + e; }
    else         { sc1 = 3; st1 = 128; pb1 = O_E1_3 + (e - 128); }
    const int sc2 = 0, st2 = 256, pb2 = O_E2_0 + e;
    int sc3, st3, pb3;
    if (e < 128) { sc3 = 0; st3 = 128; pb3 = O_E3_0 + e; }
    else         { sc3 = 1; st3 = 128; pb3 = O_E3_1 + (e - 128); }

    // ---------- chunk range for this block ----------
    const int nch = (n_nodes + CN - 1) / CN;
    const int c0  = (int)(((long long)blockIdx.x * nch) / NBLK);
    const int c1  = (int)(((long long)(blockIdx.x + 1) * nch) / NBLK);

    int* const idx_m = reinterpret_cast<int*>(&smem[IDX]);
    int* const cnt_m = reinterpret_cast<int*>(&smem[CNTO]);
    const int* idx_ro = idx_m;
    const int* cnt_ro = cnt_m;

    // ---------- staging helpers (reg-staged, issue-early / write-late) ----------
    auto stage_issue = [&](int c, fvec4& r0, fvec4& r1,
                           float& rs, int& ty, int& nv, int& total, int& cnn) {
        const long long cb = (long long)c * CN;
        cnn   = min(CN, (int)(n_nodes - cb));
        total = cnn * 14;
        nv    = total >> 2;            // max 1792 (< 2*TPB)
        const fvec4* vsrc = reinterpret_cast<const fvec4*>(x + cb * 14);
        if (tid < nv)          r0 = __builtin_nontemporal_load(vsrc + tid);
        if (tid + TPB < nv)    r1 = __builtin_nontemporal_load(vsrc + tid + TPB);
        const int sf = (nv << 2) + tid;
        if (sf < total) rs = x[cb * 14 + sf];
        if (tid < cnn)  ty = node_types[cb + tid];
    };
    auto stage_write = [&](const fvec4& r0, const fvec4& r1,
                           float rs, int nv, int total) {
        auto wr1 = [&](int i, const fvec4& v) {
            const int f = i << 2;
            int node = f / 14, col = f - node * 14;
            #pragma unroll
            for (int j = 0; j < 4; ++j) {
                smem[XSH + node * 16 + col] = v[j];
                if (++col == 14) { col = 0; ++node; }
            }
        };
        if (tid < nv)        wr1(tid, r0);
        if (tid + TPB < nv)  wr1(tid + TPB, r1);
        const int sf = (nv << 2) + tid;
        if (sf < total) { const int node = sf / 14, col = sf - node * 14; smem[XSH + node * 16 + col] = rs; }
    };

    // ---------- compute one chunk: 4 sequential type-specialized loops ----------
    auto do_chunk = [&](int c) {
        const long long cb = (long long)c * CN;
        TYPE_BLOCK(0, 11, W0, b0, sc0, st0, pb0,
            acc = fmaf(w[0],  ra.x, acc);
            acc = fmaf(w[1],  ra.y, acc);
            acc = fmaf(w[2],  rb.x, acc);
            acc = fmaf(w[3],  rb.z, acc);
            acc = fmaf(w[4],  rb.w, acc);
            acc = fmaf(w[5],  rc.x, acc);
            acc = fmaf(w[6],  rc.y, acc);
            acc = fmaf(w[7],  rc.z, acc);
            acc = fmaf(w[8],  rc.w, acc);
            acc = fmaf(w[9],  rd.x, acc);
            acc = fmaf(w[10], rd.y, acc);)
        TYPE_BLOCK(1, 12, W1, b1, sc1, st1, pb1,
            acc = fmaf(w[0],  ra.x, acc);
            acc = fmaf(w[1],  ra.y, acc);
            acc = fmaf(w[2],  rb.x, acc);
            acc = fmaf(w[3],  rb.y, acc);
            acc = fmaf(w[4],  rb.z, acc);
            acc = fmaf(w[5],  rb.w, acc);
            acc = fmaf(w[6],  rc.x, acc);
            acc = fmaf(w[7],  rc.y, acc);
            acc = fmaf(w[8],  rc.z, acc);
            acc = fmaf(w[9],  rc.w, acc);
            acc = fmaf(w[10], rd.x, acc);
            acc = fmaf(w[11], rd.y, acc);)
        TYPE_BLOCK(2, 12, W2, b2, sc2, st2, pb2,
            acc = fmaf(w[0],  ra.y, acc);
            acc = fmaf(w[1],  ra.z, acc);
            acc = fmaf(w[2],  rb.x, acc);
            acc = fmaf(w[3],  rb.y, acc);
            acc = fmaf(w[4],  rb.z, acc);
            acc = fmaf(w[5],  rb.w, acc);
            acc = fmaf(w[6],  rc.x, acc);
            acc = fmaf(w[7],  rc.y, acc);
            acc = fmaf(w[8],  rc.z, acc);
            acc = fmaf(w[9],  rc.w, acc);
            acc = fmaf(w[10], rd.x, acc);
            acc = fmaf(w[11], rd.y, acc);)
        TYPE_BLOCK(3, 12, W3, b3, sc3, st3, pb3,
            acc = fmaf(w[0],  ra.z, acc);
            acc = fmaf(w[1],  ra.w, acc);
            acc = fmaf(w[2],  rb.x, acc);
            acc = fmaf(w[3],  rb.y, acc);
            acc = fmaf(w[4],  rb.z, acc);
            acc = fmaf(w[5],  rb.w, acc);
            acc = fmaf(w[6],  rc.x, acc);
            acc = fmaf(w[7],  rc.y, acc);
            acc = fmaf(w[8],  rc.z, acc);
            acc = fmaf(w[9],  rc.w, acc);
            acc = fmaf(w[10], rd.x, acc);
            acc = fmaf(w[11], rd.y, acc);)
    };

    // ---------- prologue: stage + bucket first chunk ----------
    {
        fvec4 r0, r1; float rs = 0.f; int ty = 0, nv = 0, total = 0, cnn = 0;
        if (c0 < c1) {
            stage_issue(c0, r0, r1, rs, ty, nv, total, cnn);
            stage_write(r0, r1, rs, nv, total);
            if (tid < 4) cnt_m[tid] = 0;
        }
        __syncthreads();
        if (c0 < c1 && tid < cnn) {
            const int p = atomicAdd(&cnt_m[ty], 1);
            idx_m[ty * CN + p] = tid;
        }
        __syncthreads();
    }

    // ---------- main loop: compute chunk c while staging+bucketing c+1 ----------
    for (int c = c0; c < c1; ++c) {
        fvec4 r0, r1; float rs = 0.f; int ty = 0, nv = 0, total = 0, cnn = 0;
        const bool hasnext = (c + 1 < c1);
        if (hasnext) stage_issue(c + 1, r0, r1, rs, ty, nv, total, cnn);
        do_chunk(c);
        __syncthreads();                    // all reads of xsh/idx done
        if (hasnext) {
            stage_write(r0, r1, rs, nv, total);
            if (tid < 4) cnt_m[tid] = 0;
        }
        __syncthreads();                    // xsh written, counters zeroed
        if (hasnext && tid < cnn) {
            const int p = atomicAdd(&cnt_m[ty], 1);
            idx_m[ty * CN + p] = tid;
        }
        __syncthreads();                    // lists ready for next iteration
    }
}

extern "C" void kernel_launch(void* const* d_in, const int* in_sizes, int n_in,
                              void* d_out, int out_size, void* d_ws, size_t ws_size,
                              hipStream_t stream) {
    // setup_inputs() dict order:
    //  0:x  1:node_types  2:W0 3:b0 4:E0_2 5:E0_3 6:E0_5
    //  7:W1 8:b1 9:E1_2 10:E1_3  11:W2 12:b2 13:E2_0  14:W3 15:b3 16:E3_0 17:E3_1
    const float* xp   = (const float*)d_in[0];
    const int*   ntp  = (const int*)d_in[1];
    const float* W0 = (const float*)d_in[2];
    const float* b0 = (const float*)d_in[3];
    const float* E0_2 = (const float*)d_in[4];
    const float* E0_3 = (const float*)d_in[5];
    const float* E0_5 = (const float*)d_in[6];
    const float* W1 = (const float*)d_in[7];
    const float* b1 = (const float*)d_in[8];
    const float* E1_2 = (const float*)d_in[9];
    const float* E1_3 = (const float*)d_in[10];
    const float* W2 = (const float*)d_in[11];
    const float* b2 = (const float*)d_in[12];
    const float* E2_0 = (const float*)d_in[13];
    const float* W3 = (const float*)d_in[14];
    const float* b3 = (const float*)d_in[15];
    const float* E3_0 = (const float*)d_in[16];
    const float* E3_1 = (const float*)d_in[17];
    float* outp = (float*)d_out;

    const int n_nodes = in_sizes[1];

    hipFuncSetAttribute(reinterpret_cast<const void*>(node_enc_kernel),
                        hipFuncAttributeMaxDynamicSharedMemorySize, SMEM_BYTES);

    node_enc_kernel<<<NBLK, TPB, SMEM_BYTES, stream>>>(
        xp, ntp, W0, b0, E0_2, E0_3, E0_5, W1, b1, E1_2, E1_3,
        W2, b2, E2_0, W3, b3, E3_0, E3_1, outp, n_nodes);
}

// Round 8
// 133.288 us; speedup vs baseline: 6.8139x; 1.1700x over previous
//
#include <hip/hip_runtime.h>

typedef float fvec4 __attribute__((ext_vector_type(4)));

#define NBLK 256
#define TPB  1024
#define NG   16             // node-interleave groups (tid>>6)
#define CN   512            // nodes per chunk

// Defeat LICM: opaque pointer so the 4 type blocks' weight loads cannot be
// merged/hoisted into one 192-float live set (the R2-R6 spill disease).
#define LAUNDER_PTR(p) asm volatile("" : "+v"(p))

// ---- LDS layout (float offsets) ----
#define O_E0_2 0            // 96*86  = 8256
#define O_E0_3 8256         // 8*85   = 680
#define O_E0_5 8936         // 2*85   = 170  (pad 2)
#define O_E1_2 9108         // 4*128  = 512
#define O_E1_3 9620         // 22*128 = 2816
#define O_E2_0 12436        // 6*256  = 1536
#define O_E3_0 13972        // 15*128 = 1920
#define O_E3_1 15892        // 96*128 = 12288
#define NTAB   28180
#define XSH    NTAB                 // CN*16 floats (rows padded 14->16)
#define IDX    (XSH + CN * 16)      // 4*CN ints: per-type node index lists
#define CNTO   (IDX + 4 * CN)       // 4 ints: per-type counts
#define SMEM_FLOATS (CNTO + 4)      // 38424
#define SMEM_BYTES  (SMEM_FLOATS * 4)   // 153696 B < 160 KiB

extern __shared__ float smem[];

#define FMA4(K, XV)                                   \
    acc.x = fmaf(w[0][K], (XV), acc.x);               \
    acc.y = fmaf(w[1][K], (XV), acc.y);               \
    acc.z = fmaf(w[2][K], (XV), acc.z);               \
    acc.w = fmaf(w[3][K], (XV), acc.w);

// One type-specialized node loop; thread owns output cols 4q..4q+3.
// Inner g-loop: LDS reads + FMAs + ONE dwordx4 store. No global loads.
#define TYPE_BLOCK(T, NW, WPTR, BPTR, DESC_STMT, FMA_LIST)                     \
  {                                                                            \
    const int m = cnt_ro[T];                                                   \
    const float* Wp = WPTR; LAUNDER_PTR(Wp);                                   \
    const float* bp = BPTR; LAUNDER_PTR(bp);                                   \
    float w[4][NW];                                                            \
    _Pragma("unroll")                                                          \
    for (int j = 0; j < 4; ++j) {                                              \
      _Pragma("unroll")                                                        \
      for (int k = 0; k < NW; ++k) w[j][k] = Wp[(4 * q + j) * NW + k];         \
    }                                                                          \
    float4 bias;                                                               \
    bias.x = bp[4 * q]; bias.y = bp[4 * q + 1];                                \
    bias.z = bp[4 * q + 2]; bias.w = bp[4 * q + 3];                            \
    int sc[4], st[4], pb[4];                                                   \
    _Pragma("unroll")                                                          \
    for (int j = 0; j < 4; ++j) { const int col = 4 * q + j; DESC_STMT }       \
    for (int g = h; g < m; g += NG) {                                          \
      const int nl = idx_ro[T * CN + g];                                       \
      const float* xr = &smem[XSH + nl * 16];                                  \
      const float4 ra = *reinterpret_cast<const float4*>(xr);                  \
      const float4 rb = *reinterpret_cast<const float4*>(xr + 4);              \
      const float4 rc = *reinterpret_cast<const float4*>(xr + 8);              \
      const float2 rd = *reinterpret_cast<const float2*>(xr + 12);             \
      float4 acc = bias;                                                       \
      FMA_LIST                                                                 \
      float ev[4];                                                             \
      _Pragma("unroll")                                                        \
      for (int j = 0; j < 4; ++j) {                                            \
        const int code = (int)xr[sc[j]];                                       \
        ev[j] = smem[pb[j] + code * st[j]];                                    \
      }                                                                        \
      acc.x += ev[0]; acc.y += ev[1]; acc.z += ev[2]; acc.w += ev[3];          \
      *reinterpret_cast<float4*>(&out[(cb + nl) * 256 + 4 * q]) = acc;         \
    }                                                                          \
  }

__global__ __launch_bounds__(TPB, 1)
void node_enc_kernel(const float* __restrict__ x,
                     const int* __restrict__ node_types,
                     const float* __restrict__ W0, const float* __restrict__ b0,
                     const float* __restrict__ E0_2, const float* __restrict__ E0_3,
                     const float* __restrict__ E0_5,
                     const float* __restrict__ W1, const float* __restrict__ b1,
                     const float* __restrict__ E1_2, const float* __restrict__ E1_3,
                     const float* __restrict__ W2, const float* __restrict__ b2,
                     const float* __restrict__ E2_0,
                     const float* __restrict__ W3, const float* __restrict__ b3,
                     const float* __restrict__ E3_0, const float* __restrict__ E3_1,
                     float* __restrict__ out, int n_nodes)
{
    const int tid = threadIdx.x;
    const int q   = tid & 63;    // quad-column index: owns cols 4q..4q+3
    const int h   = tid >> 6;    // node-interleave group (0..15)

    // ---------- copy all embedding tables into LDS (once per block) ----------
    auto copy_tab = [&](const float* __restrict__ src, int dst, int n) {
        if ((((uintptr_t)src) & 15) == 0) {
            const int nv = n >> 2;
            for (int i = tid; i < nv; i += TPB) {
                const fvec4 v = *(reinterpret_cast<const fvec4*>(src) + i);
                *reinterpret_cast<fvec4*>(&smem[dst + (i << 2)]) = v;
            }
            for (int i = (nv << 2) + tid; i < n; i += TPB) smem[dst + i] = src[i];
        } else {
            for (int i = tid; i < n; i += TPB) smem[dst + i] = src[i];
        }
    };
    copy_tab(E0_2, O_E0_2, 8256);
    copy_tab(E0_3, O_E0_3, 680);
    copy_tab(E0_5, O_E0_5, 170);
    copy_tab(E1_2, O_E1_2, 512);
    copy_tab(E1_3, O_E1_3, 2816);
    copy_tab(E2_0, O_E2_0, 1536);
    copy_tab(E3_0, O_E3_0, 1920);
    copy_tab(E3_1, O_E3_1, 12288);

    // ---------- chunk range for this block ----------
    const int nch = (n_nodes + CN - 1) / CN;
    const int c0  = (int)(((long long)blockIdx.x * nch) / NBLK);
    const int c1  = (int)(((long long)(blockIdx.x + 1) * nch) / NBLK);

    int* const idx_m = reinterpret_cast<int*>(&smem[IDX]);
    int* const cnt_m = reinterpret_cast<int*>(&smem[CNTO]);
    const int* idx_ro = idx_m;
    const int* cnt_ro = cnt_m;

    // ---------- staging helpers (reg-staged, issue-early / write-late) ----------
    auto stage_issue = [&](int c, fvec4& r0, fvec4& r1,
                           float& rs, int& ty, int& nv, int& total, int& cnn) {
        const long long cb = (long long)c * CN;
        cnn   = min(CN, (int)(n_nodes - cb));
        total = cnn * 14;
        nv    = total >> 2;            // max 1792 (< 2*TPB)
        const fvec4* vsrc = reinterpret_cast<const fvec4*>(x + cb * 14);
        if (tid < nv)          r0 = __builtin_nontemporal_load(vsrc + tid);
        if (tid + TPB < nv)    r1 = __builtin_nontemporal_load(vsrc + tid + TPB);
        const int sf = (nv << 2) + tid;
        if (sf < total) rs = x[cb * 14 + sf];
        if (tid < cnn)  ty = node_types[cb + tid];
    };
    auto stage_write = [&](const fvec4& r0, const fvec4& r1,
                           float rs, int nv, int total) {
        auto wr1 = [&](int i, const fvec4& v) {
            const int f = i << 2;
            int node = f / 14, col = f - node * 14;
            #pragma unroll
            for (int j = 0; j < 4; ++j) {
                smem[XSH + node * 16 + col] = v[j];
                if (++col == 14) { col = 0; ++node; }
            }
        };
        if (tid < nv)        wr1(tid, r0);
        if (tid + TPB < nv)  wr1(tid + TPB, r1);
        const int sf = (nv << 2) + tid;
        if (sf < total) { const int node = sf / 14, col = sf - node * 14; smem[XSH + node * 16 + col] = rs; }
    };

    // ---------- compute one chunk: 4 sequential type-specialized loops ----------
    auto do_chunk = [&](int c) {
        const long long cb = (long long)c * CN;
        TYPE_BLOCK(0, 11, W0, b0,
            if (col < 86)       { sc[j] = 2; st[j] = 86; pb[j] = O_E0_2 + col; }
            else if (col < 171) { sc[j] = 3; st[j] = 85; pb[j] = O_E0_3 + col - 86; }
            else                { sc[j] = 5; st[j] = 85; pb[j] = O_E0_5 + col - 171; },
            FMA4(0,  ra.x) FMA4(1,  ra.y) FMA4(2,  rb.x) FMA4(3,  rb.z)
            FMA4(4,  rb.w) FMA4(5,  rc.x) FMA4(6,  rc.y) FMA4(7,  rc.z)
            FMA4(8,  rc.w) FMA4(9,  rd.x) FMA4(10, rd.y))
        TYPE_BLOCK(1, 12, W1, b1,
            if (col < 128) { sc[j] = 2; st[j] = 128; pb[j] = O_E1_2 + col; }
            else           { sc[j] = 3; st[j] = 128; pb[j] = O_E1_3 + col - 128; },
            FMA4(0,  ra.x) FMA4(1,  ra.y) FMA4(2,  rb.x) FMA4(3,  rb.y)
            FMA4(4,  rb.z) FMA4(5,  rb.w) FMA4(6,  rc.x) FMA4(7,  rc.y)
            FMA4(8,  rc.z) FMA4(9,  rc.w) FMA4(10, rd.x) FMA4(11, rd.y))
        TYPE_BLOCK(2, 12, W2, b2,
            sc[j] = 0; st[j] = 256; pb[j] = O_E2_0 + col;,
            FMA4(0,  ra.y) FMA4(1,  ra.z) FMA4(2,  rb.x) FMA4(3,  rb.y)
            FMA4(4,  rb.z) FMA4(5,  rb.w) FMA4(6,  rc.x) FMA4(7,  rc.y)
            FMA4(8,  rc.z) FMA4(9,  rc.w) FMA4(10, rd.x) FMA4(11, rd.y))
        TYPE_BLOCK(3, 12, W3, b3,
            if (col < 128) { sc[j] = 0; st[j] = 128; pb[j] = O_E3_0 + col; }
            else           { sc[j] = 1; st[j] = 128; pb[j] = O_E3_1 + col - 128; },
            FMA4(0,  ra.z) FMA4(1,  ra.w) FMA4(2,  rb.x) FMA4(3,  rb.y)
            FMA4(4,  rb.z) FMA4(5,  rb.w) FMA4(6,  rc.x) FMA4(7,  rc.y)
            FMA4(8,  rc.z) FMA4(9,  rc.w) FMA4(10, rd.x) FMA4(11, rd.y))
    };

    // ---------- prologue: stage + bucket first chunk ----------
    {
        fvec4 r0, r1; float rs = 0.f; int ty = 0, nv = 0, total = 0, cnn = 0;
        if (c0 < c1) {
            stage_issue(c0, r0, r1, rs, ty, nv, total, cnn);
            stage_write(r0, r1, rs, nv, total);
            if (tid < 4) cnt_m[tid] = 0;
        }
        __syncthreads();
        if (c0 < c1 && tid < cnn) {
            const int p = atomicAdd(&cnt_m[ty], 1);
            idx_m[ty * CN + p] = tid;
        }
        __syncthreads();
    }

    // ---------- main loop: compute chunk c while staging+bucketing c+1 ----------
    for (int c = c0; c < c1; ++c) {
        fvec4 r0, r1; float rs = 0.f; int ty = 0, nv = 0, total = 0, cnn = 0;
        const bool hasnext = (c + 1 < c1);
        if (hasnext) stage_issue(c + 1, r0, r1, rs, ty, nv, total, cnn);
        do_chunk(c);
        __syncthreads();                    // all reads of xsh/idx done
        if (hasnext) {
            stage_write(r0, r1, rs, nv, total);
            if (tid < 4) cnt_m[tid] = 0;
        }
        __syncthreads();                    // xsh written, counters zeroed
        if (hasnext && tid < cnn) {
            const int p = atomicAdd(&cnt_m[ty], 1);
            idx_m[ty * CN + p] = tid;
        }
        __syncthreads();                    // lists ready for next iteration
    }
}

extern "C" void kernel_launch(void* const* d_in, const int* in_sizes, int n_in,
                              void* d_out, int out_size, void* d_ws, size_t ws_size,
                              hipStream_t stream) {
    // setup_inputs() dict order:
    //  0:x  1:node_types  2:W0 3:b0 4:E0_2 5:E0_3 6:E0_5
    //  7:W1 8:b1 9:E1_2 10:E1_3  11:W2 12:b2 13:E2_0  14:W3 15:b3 16:E3_0 17:E3_1
    const float* xp   = (const float*)d_in[0];
    const int*   ntp  = (const int*)d_in[1];
    const float* W0 = (const float*)d_in[2];
    const float* b0 = (const float*)d_in[3];
    const float* E0_2 = (const float*)d_in[4];
    const float* E0_3 = (const float*)d_in[5];
    const float* E0_5 = (const float*)d_in[6];
    const float* W1 = (const float*)d_in[7];
    const float* b1 = (const float*)d_in[8];
    const float* E1_2 = (const float*)d_in[9];
    const float* E1_3 = (const float*)d_in[10];
    const float* W2 = (const float*)d_in[11];
    const float* b2 = (const float*)d_in[12];
    const float* E2_0 = (const float*)d_in[13];
    const float* W3 = (const float*)d_in[14];
    const float* b3 = (const float*)d_in[15];
    const float* E3_0 = (const float*)d_in[16];
    const float* E3_1 = (const float*)d_in[17];
    float* outp = (float*)d_out;

    const int n_nodes = in_sizes[1];

    hipFuncSetAttribute(reinterpret_cast<const void*>(node_enc_kernel),
                        hipFuncAttributeMaxDynamicSharedMemorySize, SMEM_BYTES);

    node_enc_kernel<<<NBLK, TPB, SMEM_BYTES, stream>>>(
        xp, ntp, W0, b0, E0_2, E0_3, E0_5, W1, b1, E1_2, E1_3,
        W2, b2, E2_0, W3, b3, E3_0, E3_1, outp, n_nodes);
}

// Round 10
// 127.283 us; speedup vs baseline: 7.1354x; 1.0472x over previous
//
#include <hip/hip_runtime.h>

typedef float fvec4 __attribute__((ext_vector_type(4)));

#define NBLK 256
#define TPB  1024
#define NG   16             // waves per block (node-interleave groups)
#define CN   512            // nodes per chunk

// Defeat LICM: opaque pointer so the 4 type blocks' weight loads cannot be
// merged/hoisted into one 192-float live set (the R2-R6 spill disease).
#define LAUNDER_PTR(p) asm volatile("" : "+v"(p))

// ---- LDS layout (float offsets) ----
// Type-0 tables padded to row stride 88 floats, with base offsets chosen so
// (base - first_col) % 4 == 0  =>  base + code*88 + (4q - first_col) stays
// 16B-aligned for the vectorized gather.
#define O_E0_2 0            // 96 x 88 = 8448          (0 % 4 == 0)
#define O_E0_3 8450         // 8  x 88 = 704  -> 9154  (8450-86  = 8364 % 4 == 0)
#define O_E0_5 9155         // 2  x 88 = 176  -> 9331  (9155-171 = 8984 % 4 == 0)
#define O_E1_2 9332         // 4  x 128 = 512
#define O_E1_3 9844         // 22 x 128 = 2816         (9844-128 = 9716 % 4 == 0)
#define O_E2_0 12660        // 6  x 256 = 1536
#define O_E3_0 14196        // 15 x 128 = 1920
#define O_E3_1 16116        // 96 x 128 = 12288        (16116-128 = 15988 % 4 == 0)
#define NTAB   28404
#define XSH    NTAB                 // CN*16 floats (rows padded 14->16)
#define IDX    (XSH + CN * 16)      // 4*CN ints: per-type node index lists
#define CNTO   (IDX + 4 * CN)       // 4 ints: per-type counts
#define SMEM_FLOATS (CNTO + 4)      // 38648
#define SMEM_BYTES  (SMEM_FLOATS * 4)   // 154592 B < 160 KiB

extern __shared__ float smem[];

#define FMA4(K, XV)                                   \
    acc.x = fmaf(w[0][K], (XV), acc.x);               \
    acc.y = fmaf(w[1][K], (XV), acc.y);               \
    acc.z = fmaf(w[2][K], (XV), acc.z);               \
    acc.w = fmaf(w[3][K], (XV), acc.w);

__global__ __launch_bounds__(TPB, 1)
void node_enc_kernel(const float* __restrict__ x,
                     const int* __restrict__ node_types,
                     const float* __restrict__ W0, const float* __restrict__ b0,
                     const float* __restrict__ E0_2, const float* __restrict__ E0_3,
                     const float* __restrict__ E0_5,
                     const float* __restrict__ W1, const float* __restrict__ b1,
                     const float* __restrict__ E1_2, const float* __restrict__ E1_3,
                     const float* __restrict__ W2, const float* __restrict__ b2,
                     const float* __restrict__ E2_0,
                     const float* __restrict__ W3, const float* __restrict__ b3,
                     const float* __restrict__ E3_0, const float* __restrict__ E3_1,
                     float* __restrict__ out, int n_nodes)
{
    const int tid = threadIdx.x;
    const int q   = tid & 63;    // lane: owns output cols 4q..4q+3
    const int h   = tid >> 6;    // wave index within block (0..15)

    // ---------- copy embedding tables into LDS (once per block) ----------
    auto copy_tab = [&](const float* __restrict__ src, int dst, int n) {
        if ((((uintptr_t)src) & 15) == 0) {
            const int nv = n >> 2;
            for (int i = tid; i < nv; i += TPB) {
                const fvec4 v = *(reinterpret_cast<const fvec4*>(src) + i);
                *reinterpret_cast<fvec4*>(&smem[dst + (i << 2)]) = v;
            }
            for (int i = (nv << 2) + tid; i < n; i += TPB) smem[dst + i] = src[i];
        } else {
            for (int i = tid; i < n; i += TPB) smem[dst + i] = src[i];
        }
    };
    auto copy_tab_pad = [&](const float* __restrict__ src, int dst, int rows, int cols) {
        const int n = rows * cols;
        for (int i = tid; i < n; i += TPB) {
            const int r = i / cols, c2 = i - r * cols;
            smem[dst + r * 88 + c2] = src[i];
        }
    };
    copy_tab_pad(E0_2, O_E0_2, 96, 86);
    copy_tab_pad(E0_3, O_E0_3, 8, 85);
    copy_tab_pad(E0_5, O_E0_5, 2, 85);
    copy_tab(E1_2, O_E1_2, 512);
    copy_tab(E1_3, O_E1_3, 2816);
    copy_tab(E2_0, O_E2_0, 1536);
    copy_tab(E3_0, O_E3_0, 1920);
    copy_tab(E3_1, O_E3_1, 12288);

    // ---------- chunk range for this block ----------
    const int nch = (n_nodes + CN - 1) / CN;
    const int c0  = (int)(((long long)blockIdx.x * nch) / NBLK);
    const int c1  = (int)(((long long)(blockIdx.x + 1) * nch) / NBLK);

    int* const idx_m = reinterpret_cast<int*>(&smem[IDX]);
    int* const cnt_m = reinterpret_cast<int*>(&smem[CNTO]);
    const int* idx_ro = idx_m;
    const int* cnt_ro = cnt_m;

    // ---------- staging helpers (reg-staged, issue-early / write-late) ----------
    auto stage_issue = [&](int c, fvec4& r0, fvec4& r1,
                           float& rs, int& ty, int& nv, int& total, int& cnn) {
        const long long cb = (long long)c * CN;
        cnn   = min(CN, (int)(n_nodes - cb));
        total = cnn * 14;
        nv    = total >> 2;            // max 1792 (< 2*TPB)
        const fvec4* vsrc = reinterpret_cast<const fvec4*>(x + cb * 14);
        if (tid < nv)          r0 = __builtin_nontemporal_load(vsrc + tid);
        if (tid + TPB < nv)    r1 = __builtin_nontemporal_load(vsrc + tid + TPB);
        const int sf = (nv << 2) + tid;
        if (sf < total) rs = x[cb * 14 + sf];
        if (tid < cnn)  ty = node_types[cb + tid];
    };
    auto stage_write = [&](const fvec4& r0, const fvec4& r1,
                           float rs, int nv, int total) {
        auto wr1 = [&](int i, const fvec4& v) {
            const int f = i << 2;
            int node = f / 14, col = f - node * 14;
            #pragma unroll
            for (int j = 0; j < 4; ++j) {
                smem[XSH + node * 16 + col] = v[j];
                if (++col == 14) { col = 0; ++node; }
            }
        };
        if (tid < nv)        wr1(tid, r0);
        if (tid + TPB < nv)  wr1(tid + TPB, r1);
        const int sf = (nv << 2) + tid;
        if (sf < total) { const int node = sf / 14, col = sf - node * 14; smem[XSH + node * 16 + col] = rs; }
    };

    // ---------- compute one chunk: 4 sequential type-specialized loops ----------
    auto do_chunk = [&](int c) {
        const long long cb = (long long)c * CN;

        // ===== type 0 (11 cont cols; emb segments [0,86) E0_2, [86,171) E0_3, [171,256) E0_5) =====
        {
            const int m = cnt_ro[0];
            const float* Wp = W0; LAUNDER_PTR(Wp);
            const float* bp = b0; LAUNDER_PTR(bp);
            float w[4][11];
            #pragma unroll
            for (int j = 0; j < 4; ++j) {
                #pragma unroll
                for (int k = 0; k < 11; ++k) w[j][k] = Wp[(4 * q + j) * 11 + k];
            }
            float4 bias;
            bias.x = bp[4 * q]; bias.y = bp[4 * q + 1];
            bias.z = bp[4 * q + 2]; bias.w = bp[4 * q + 3];
            int scv, ebase;
            const bool fb = (q == 21) || (q == 42);
            if (q <= 21)      { scv = 2; ebase = O_E0_2 + 4 * q; }
            else if (q <= 42) { scv = 3; ebase = (O_E0_3 - 86) + 4 * q; }
            else              { scv = 5; ebase = (O_E0_5 - 171) + 4 * q; }
            for (int g = h; g < m; g += NG) {
                const int nl = idx_ro[0 * CN + g];
                const float* xr = &smem[XSH + nl * 16];
                const float4 ra = *reinterpret_cast<const float4*>(xr);
                const float4 rb = *reinterpret_cast<const float4*>(xr + 4);
                const float4 rc = *reinterpret_cast<const float4*>(xr + 8);
                const float2 rd = *reinterpret_cast<const float2*>(xr + 12);
                float4 acc = bias;
                FMA4(0,  ra.x) FMA4(1,  ra.y) FMA4(2,  rb.x) FMA4(3,  rb.z)
                FMA4(4,  rb.w) FMA4(5,  rc.x) FMA4(6,  rc.y) FMA4(7,  rc.z)
                FMA4(8,  rc.w) FMA4(9,  rd.x) FMA4(10, rd.y)
                float4 ev;
                if (fb) {
                    if (q == 21) {
                        const int c2 = (int)xr[2], c3 = (int)xr[3];
                        ev.x = smem[O_E0_2 + c2 * 88 + 84];
                        ev.y = smem[O_E0_2 + c2 * 88 + 85];
                        ev.z = smem[O_E0_3 + c3 * 88 + 0];
                        ev.w = smem[O_E0_3 + c3 * 88 + 1];
                    } else {
                        const int c3 = (int)xr[3], c5 = (int)xr[5];
                        ev.x = smem[O_E0_3 + c3 * 88 + 82];
                        ev.y = smem[O_E0_3 + c3 * 88 + 83];
                        ev.z = smem[O_E0_3 + c3 * 88 + 84];
                        ev.w = smem[O_E0_5 + c5 * 88 + 0];
                    }
                } else {
                    const int code = (int)xr[scv];
                    ev = *reinterpret_cast<const float4*>(&smem[ebase + code * 88]);
                }
                acc.x += ev.x; acc.y += ev.y; acc.z += ev.z; acc.w += ev.w;
                *reinterpret_cast<float4*>(&out[(cb + nl) * 256 + 4 * q]) = acc;
            }
        }

        // ===== type 1 (12 cont cols; emb [0,128) E1_2, [128,256) E1_3) =====
        {
            const int m = cnt_ro[1];
            const float* Wp = W1; LAUNDER_PTR(Wp);
            const float* bp = b1; LAUNDER_PTR(bp);
            float w[4][12];
            #pragma unroll
            for (int j = 0; j < 4; ++j) {
                #pragma unroll
                for (int k = 0; k < 12; ++k) w[j][k] = Wp[(4 * q + j) * 12 + k];
            }
            float4 bias;
            bias.x = bp[4 * q]; bias.y = bp[4 * q + 1];
            bias.z = bp[4 * q + 2]; bias.w = bp[4 * q + 3];
            const int scv   = (q < 32) ? 2 : 3;
            const int ebase = ((q < 32) ? O_E1_2 : (O_E1_3 - 128)) + 4 * q;
            for (int g = h; g < m; g += NG) {
                const int nl = idx_ro[1 * CN + g];
                const float* xr = &smem[XSH + nl * 16];
                const float4 ra = *reinterpret_cast<const float4*>(xr);
                const float4 rb = *reinterpret_cast<const float4*>(xr + 4);
                const float4 rc = *reinterpret_cast<const float4*>(xr + 8);
                const float2 rd = *reinterpret_cast<const float2*>(xr + 12);
                float4 acc = bias;
                FMA4(0,  ra.x) FMA4(1,  ra.y) FMA4(2,  rb.x) FMA4(3,  rb.y)
                FMA4(4,  rb.z) FMA4(5,  rb.w) FMA4(6,  rc.x) FMA4(7,  rc.y)
                FMA4(8,  rc.z) FMA4(9,  rc.w) FMA4(10, rd.x) FMA4(11, rd.y)
                const int code = (int)xr[scv];
                const float4 ev = *reinterpret_cast<const float4*>(&smem[ebase + code * 128]);
                acc.x += ev.x; acc.y += ev.y; acc.z += ev.z; acc.w += ev.w;
                *reinterpret_cast<float4*>(&out[(cb + nl) * 256 + 4 * q]) = acc;
            }
        }

        // ===== type 2 (12 cont cols; emb E2_0 full width) =====
        {
            const int m = cnt_ro[2];
            const float* Wp = W2; LAUNDER_PTR(Wp);
            const float* bp = b2; LAUNDER_PTR(bp);
            float w[4][12];
            #pragma unroll
            for (int j = 0; j < 4; ++j) {
                #pragma unroll
                for (int k = 0; k < 12; ++k) w[j][k] = Wp[(4 * q + j) * 12 + k];
            }
            float4 bias;
            bias.x = bp[4 * q]; bias.y = bp[4 * q + 1];
            bias.z = bp[4 * q + 2]; bias.w = bp[4 * q + 3];
            const int ebase = O_E2_0 + 4 * q;
            for (int g = h; g < m; g += NG) {
                const int nl = idx_ro[2 * CN + g];
                const float* xr = &smem[XSH + nl * 16];
                const float4 ra = *reinterpret_cast<const float4*>(xr);
                const float4 rb = *reinterpret_cast<const float4*>(xr + 4);
                const float4 rc = *reinterpret_cast<const float4*>(xr + 8);
                const float2 rd = *reinterpret_cast<const float2*>(xr + 12);
                float4 acc = bias;
                FMA4(0,  ra.y) FMA4(1,  ra.z) FMA4(2,  rb.x) FMA4(3,  rb.y)
                FMA4(4,  rb.z) FMA4(5,  rb.w) FMA4(6,  rc.x) FMA4(7,  rc.y)
                FMA4(8,  rc.z) FMA4(9,  rc.w) FMA4(10, rd.x) FMA4(11, rd.y)
                const int code = (int)xr[0];
                const float4 ev = *reinterpret_cast<const float4*>(&smem[ebase + code * 256]);
                acc.x += ev.x; acc.y += ev.y; acc.z += ev.z; acc.w += ev.w;
                *reinterpret_cast<float4*>(&out[(cb + nl) * 256 + 4 * q]) = acc;
            }
        }

        // ===== type 3 (12 cont cols; emb [0,128) E3_0, [128,256) E3_1) =====
        {
            const int m = cnt_ro[3];
            const float* Wp = W3; LAUNDER_PTR(Wp);
            const float* bp = b3; LAUNDER_PTR(bp);
            float w[4][12];
            #pragma unroll
            for (int j = 0; j < 4; ++j) {
                #pragma unroll
                for (int k = 0; k < 12; ++k) w[j][k] = Wp[(4 * q + j) * 12 + k];
            }
            float4 bias;
            bias.x = bp[4 * q]; bias.y = bp[4 * q + 1];
            bias.z = bp[4 * q + 2]; bias.w = bp[4 * q + 3];
            const int scv   = (q < 32) ? 0 : 1;
            const int ebase = ((q < 32) ? O_E3_0 : (O_E3_1 - 128)) + 4 * q;
            for (int g = h; g < m; g += NG) {
                const int nl = idx_ro[3 * CN + g];
                const float* xr = &smem[XSH + nl * 16];
                const float4 ra = *reinterpret_cast<const float4*>(xr);
                const float4 rb = *reinterpret_cast<const float4*>(xr + 4);
                const float4 rc = *reinterpret_cast<const float4*>(xr + 8);
                const float2 rd = *reinterpret_cast<const float2*>(xr + 12);
                float4 acc = bias;
                FMA4(0,  ra.z) FMA4(1,  ra.w) FMA4(2,  rb.x) FMA4(3,  rb.y)
                FMA4(4,  rb.z) FMA4(5,  rb.w) FMA4(6,  rc.x) FMA4(7,  rc.y)
                FMA4(8,  rc.z) FMA4(9,  rc.w) FMA4(10, rd.x) FMA4(11, rd.y)
                const int code = (int)xr[scv];
                const float4 ev = *reinterpret_cast<const float4*>(&smem[ebase + code * 128]);
                acc.x += ev.x; acc.y += ev.y; acc.z += ev.z; acc.w += ev.w;
                *reinterpret_cast<float4*>(&out[(cb + nl) * 256 + 4 * q]) = acc;
            }
        }
    };

    // ---------- prologue: stage + bucket first chunk ----------
    {
        fvec4 r0, r1; float rs = 0.f; int ty = 0, nv = 0, total = 0, cnn = 0;
        if (c0 < c1) {
            stage_issue(c0, r0, r1, rs, ty, nv, total, cnn);
            stage_write(r0, r1, rs, nv, total);
            if (tid < 4) cnt_m[tid] = 0;
        }
        __syncthreads();
        if (c0 < c1 && tid < cnn) {
            const int p = atomicAdd(&cnt_m[ty], 1);
            idx_m[ty * CN + p] = tid;
        }
        __syncthreads();
    }

    // ---------- main loop: compute chunk c while staging+bucketing c+1 ----------
    for (int c = c0; c < c1; ++c) {
        fvec4 r0, r1; float rs = 0.f; int ty = 0, nv = 0, total = 0, cnn = 0;
        const bool hasnext = (c + 1 < c1);
        if (hasnext) stage_issue(c + 1, r0, r1, rs, ty, nv, total, cnn);
        do_chunk(c);
        __syncthreads();                    // all reads of xsh/idx done
        if (hasnext) {
            stage_write(r0, r1, rs, nv, total);
            if (tid < 4) cnt_m[tid] = 0;
        }
        __syncthreads();                    // xsh written, counters zeroed
        if (hasnext && tid < cnn) {
            const int p = atomicAdd(&cnt_m[ty], 1);
            idx_m[ty * CN + p] = tid;
        }
        __syncthreads();                    // lists ready for next iteration
    }
}

extern "C" void kernel_launch(void* const* d_in, const int* in_sizes, int n_in,
                              void* d_out, int out_size, void* d_ws, size_t ws_size,
                              hipStream_t stream) {
    // setup_inputs() dict order:
    //  0:x  1:node_types  2:W0 3:b0 4:E0_2 5:E0_3 6:E0_5
    //  7:W1 8:b1 9:E1_2 10:E1_3  11:W2 12:b2 13:E2_0  14:W3 15:b3 16:E3_0 17:E3_1
    const float* xp   = (const float*)d_in[0];
    const int*   ntp  = (const int*)d_in[1];
    const float* W0 = (const float*)d_in[2];
    const float* b0 = (const float*)d_in[3];
    const float* E0_2 = (const float*)d_in[4];
    const float* E0_3 = (const float*)d_in[5];
    const float* E0_5 = (const float*)d_in[6];
    const float* W1 = (const float*)d_in[7];
    const float* b1 = (const float*)d_in[8];
    const float* E1_2 = (const float*)d_in[9];
    const float* E1_3 = (const float*)d_in[10];
    const float* W2 = (const float*)d_in[11];
    const float* b2 = (const float*)d_in[12];
    const float* E2_0 = (const float*)d_in[13];
    const float* W3 = (const float*)d_in[14];
    const float* b3 = (const float*)d_in[15];
    const float* E3_0 = (const float*)d_in[16];
    const float* E3_1 = (const float*)d_in[17];
    float* outp = (float*)d_out;

    const int n_nodes = in_sizes[1];

    (void)hipFuncSetAttribute(reinterpret_cast<const void*>(node_enc_kernel),
                              hipFuncAttributeMaxDynamicSharedMemorySize, SMEM_BYTES);

    node_enc_kernel<<<NBLK, TPB, SMEM_BYTES, stream>>>(
        xp, ntp, W0, b0, E0_2, E0_3, E0_5, W1, b1, E1_2, E1_3,
        W2, b2, E2_0, W3, b3, E3_0, E3_1, outp, n_nodes);
}